// Round 4
// baseline (1128.121 us; speedup 1.0000x reference)
//
#include <hip/hip_runtime.h>
#include <cstdint>
#include <cstddef>

// ============================================================================
// ResMLP fused kernel for MI355X (gfx950) — round 4
//
//  - Prep (unchanged): weights -> uniform bf16 chunk-major stream ws[190][160][32]
//      c<25: embed (k pad 800), 25..184: 32 layers, 185..189: head (n pad 160).
//  - Main: grid 512 x 256 thr; 128 rows/block (exactly 2 blocks/CU, one round).
//    4 waves = 2(mg: 64 rows) x 2(ng: 80 cols); wave tile 64x80 = 4mt x 5nt.
//    acc[4][5] + resid[4][5] fp32 in regs (~160) + 2-deep B reg ring (40).
//    B direct global->VGPR, loads interleaved after each frag's last use;
//    halved per-CU vmem vs r3 (B covers 64 rows/load instead of 32).
//    Cheap H writeback: cndmask row-select + RTN(+0x8000) + dpp pair swap +
//    v_perm pack -> all 64 lanes emit packed b32, ~6 VALU + 1 DS each.
// ============================================================================

typedef __attribute__((ext_vector_type(8))) short bfrag8;   // 8 x bf16
typedef __attribute__((ext_vector_type(4))) float facc4;    // 4 x f32

#define MFMA16(a, b, c) __builtin_amdgcn_mfma_f32_16x16x32_bf16((a), (b), (c), 0, 0, 0)

static __device__ __forceinline__ uint16_t f2bf16u(float v) {
    uint32_t u = __builtin_bit_cast(uint32_t, v);
    uint32_t r = u + 0x7FFFu + ((u >> 16) & 1u);
    return (uint16_t)(r >> 16);
}
static __device__ __forceinline__ uint32_t pack2_bf16(float lo, float hi) {
    return (uint32_t)f2bf16u(lo) | ((uint32_t)f2bf16u(hi) << 16);
}
static __device__ __forceinline__ uint32_t rtn_bits(float f) {   // round-half-up bf16, keep in hi16
    return __builtin_bit_cast(uint32_t, f) + 0x8000u;
}

// ---------------------------------------------------------------------------
// Prep: transpose + cast weights into the uniform chunk-major stream.
// ---------------------------------------------------------------------------
__global__ __launch_bounds__(256) void resmlp_prep(
    const float* __restrict__ embed_w, const float* __restrict__ layer_w,
    const float* __restrict__ head_w, uint16_t* __restrict__ ws)
{
    int b = blockIdx.x;
    if (b == 925) {
        for (int idx = threadIdx.x; idx < 25600; idx += 256) {
            int n = idx / 160, k = idx - n * 160;
            float v = (n < 10) ? head_w[k * 10 + n] : 0.f;
            ws[(size_t)(185 + (k >> 5)) * 5120 + n * 32 + (k & 31)] = f2bf16u(v);
        }
        return;
    }
    __shared__ float tile[32][33];
    const float* src; int R, rt, ct; size_t chunkBase;
    if (b < 800) {
        int l = b / 25, t = b % 25; rt = t / 5; ct = t % 5;
        src = layer_w + (size_t)l * 25600; R = 160;
        chunkBase = (size_t)(25 + l * 5 + rt) * 5120;
    } else {
        int t = b - 800; rt = t / 5; ct = t % 5;
        src = embed_w; R = 784;
        chunkBase = (size_t)rt * 5120;
    }
    int tx = threadIdx.x & 31, ty = threadIdx.x >> 5;
#pragma unroll
    for (int j = 0; j < 4; ++j) {
        int r = rt * 32 + ty + j * 8, c = ct * 32 + tx;   // r=k, c=n
        tile[ty + j * 8][tx] = (r < R) ? src[(size_t)r * 160 + c] : 0.f;
    }
    __syncthreads();
#pragma unroll
    for (int j = 0; j < 4; ++j) {
        int n = ct * 32 + ty + j * 8;
        ws[chunkBase + n * 32 + tx] = f2bf16u(tile[tx][ty + j * 8]);
    }
}

// ---------------------------------------------------------------------------
// stage_x: 128 rows x 160-col chunk of x -> Hs (bf16, row stride 168 elems)
// ---------------------------------------------------------------------------
__device__ __forceinline__ void stage_x_group(const float* __restrict__ x,
                                              uint16_t* Hs, int r0, int tid, int g)
{
    const int row = tid >> 1;          // 0..127
    const int h2  = tid & 1;
    const int kc  = g * 160;
    const float* xr = x + (size_t)(r0 + row) * 784 + kc;
#pragma unroll
    for (int j = 0; j < 20; ++j) {
        int c4 = h2 + j * 2;           // 0..39 float4 index inside chunk
        float4 v;
        if (kc + c4 * 4 < 784) v = *(const float4*)(xr + c4 * 4);
        else                   v = make_float4(0.f, 0.f, 0.f, 0.f);
        uint2 u;
        u.x = pack2_bf16(v.x, v.y);
        u.y = pack2_bf16(v.z, v.w);
        *(uint2*)((char*)Hs + row * 336 + c4 * 8) = u;
    }
}

// ---------------------------------------------------------------------------
__global__ __launch_bounds__(256, 2) void resmlp_main(
    const float* __restrict__ x,
    const float* __restrict__ embed_b,
    const float* __restrict__ head_b,
    const uint16_t* __restrict__ ws,
    float* __restrict__ out)
{
    __shared__ __align__(16) uint16_t Hs[128 * 168];   // 43008 B

    const int tid  = threadIdx.x;
    const int lane = tid & 63;
    const int wave = tid >> 6;
    const int mg = wave >> 1;          // 0..1  row group (64 rows)
    const int ng = wave & 1;           // 0..1  col group (80 cols)
    const int q  = lane >> 4;          // 0..3
    const int ln = lane & 15;          // 0..15
    const int NB = ng * 80;
    const int r0 = blockIdx.x * 128;
    const bool oddl = (ln & 1) != 0;
    const uint32_t psel = oddl ? 0x03020706u : 0x07060302u;

    float bias[5];
#pragma unroll
    for (int nt = 0; nt < 5; ++nt) bias[nt] = embed_b[NB + nt * 16 + ln];
    const float hb = (ln < 10) ? head_b[ln] : 0.f;

    facc4 acc[4][5];
    facc4 resid[4][5];
    bfrag8 B0[5], B1[5];
#pragma unroll
    for (int mt = 0; mt < 4; ++mt)
#pragma unroll
        for (int nt = 0; nt < 5; ++nt) acc[mt][nt] = (facc4){0.f, 0.f, 0.f, 0.f};

    const uint16_t* wlane = ws + (NB + ln) * 32 + q * 8;

    // ---- prologue: stage x group 0; preload B chunks 0,1 ----
    stage_x_group(x, Hs, r0, tid, 0);
#pragma unroll
    for (int nt = 0; nt < 5; ++nt) {
        B0[nt] = *(const bfrag8*)(wlane + 0 * 5120 + nt * 512);
        B1[nt] = *(const bfrag8*)(wlane + 1 * 5120 + nt * 512);
    }
    __syncthreads();

    const int abase = (mg * 64 + ln) * 168 + q * 8;
    const uint16_t* wp = wlane + 2 * 5120;
    // writeback base byte address (row part without mt/rl, col part without nt)
    const int wb_base = (mg * 64 + q * 4 + (ln & 1)) * 336 + (NB + (ln & ~1)) * 2;

    for (int p = 0; p < 19; ++p) {
#pragma unroll
        for (int jj = 0; jj < 10; ++jj) {
            const int akk = jj % 5;                   // compile-time

            // A fragments at use (compiler hoists ds_reads within unrolled body)
            bfrag8 A0 = *(const bfrag8*)(Hs + abase + 0 * (16 * 168) + akk * 32);
            bfrag8 A1 = *(const bfrag8*)(Hs + abase + 1 * (16 * 168) + akk * 32);
            bfrag8 A2 = *(const bfrag8*)(Hs + abase + 2 * (16 * 168) + akk * 32);
            bfrag8 A3 = *(const bfrag8*)(Hs + abase + 3 * (16 * 168) + akk * 32);

            bfrag8* Bc = (jj & 1) ? B1 : B0;
#pragma unroll
            for (int nt = 0; nt < 5; ++nt) {
                acc[0][nt] = MFMA16(A0, Bc[nt], acc[0][nt]);
                acc[1][nt] = MFMA16(A1, Bc[nt], acc[1][nt]);
                acc[2][nt] = MFMA16(A2, Bc[nt], acc[2][nt]);
                acc[3][nt] = MFMA16(A3, Bc[nt], acc[3][nt]);
                // reload this frag (for chunk c+2) right after its last use
                if (jj < 8 || p < 18)
                    Bc[nt] = *(const bfrag8*)(wp + nt * 512);
            }
            if (jj < 8 || p < 18) wp += 5120;

            // ---- panel boundary every 5 chunks ----
            if (jj == 4 || jj == 9) {
                const int qp = p * 2 + (jj == 9);     // 0..37
                __syncthreads();                      // all A reads of panel done
                if (qp < 4) {
                    stage_x_group(x, Hs, r0, tid, qp + 1);
                } else if (qp < 37) {
                    if (qp == 4) {
#pragma unroll
                        for (int mt = 0; mt < 4; ++mt)
#pragma unroll
                            for (int nt = 0; nt < 5; ++nt)
#pragma unroll
                                for (int r = 0; r < 4; ++r)
                                    resid[mt][nt][r] = acc[mt][nt][r] + bias[nt];
                    } else {
#pragma unroll
                        for (int mt = 0; mt < 4; ++mt)
#pragma unroll
                            for (int nt = 0; nt < 5; ++nt)
#pragma unroll
                                for (int r = 0; r < 4; ++r)
                                    resid[mt][nt][r] += fmaxf(acc[mt][nt][r], 0.f);
                    }
                    // zero acc + writeback H (all lanes active)
#pragma unroll
                    for (int mt = 0; mt < 4; ++mt) {
#pragma unroll
                        for (int nt = 0; nt < 5; ++nt) {
                            acc[mt][nt] = (facc4){0.f, 0.f, 0.f, 0.f};
#pragma unroll
                            for (int pr = 0; pr < 2; ++pr) {
                                const int rl = pr * 2;
                                float a = oddl ? resid[mt][nt][rl + 1] : resid[mt][nt][rl];     // my row
                                float bx = oddl ? resid[mt][nt][rl]    : resid[mt][nt][rl + 1]; // partner row, my col
                                uint32_t br = rtn_bits(bx);
                                uint32_t pb = (uint32_t)__builtin_amdgcn_mov_dpp(
                                    (int)br, 0xB1, 0xF, 0xF, true);        // pair swap
                                uint32_t pk = __builtin_amdgcn_perm(pb, rtn_bits(a), psel);
                                *(uint32_t*)((char*)Hs + wb_base +
                                             mt * (16 * 336) + rl * 336 + nt * 32) = pk;
                            }
                        }
                    }
                } else {
                    // qp == 37: head epilogue + store
                    if (ng == 0) {
#pragma unroll
                        for (int mt = 0; mt < 4; ++mt)
#pragma unroll
                            for (int r = 0; r < 4; ++r) {
                                int row = r0 + mg * 64 + mt * 16 + q * 4 + r;
                                if (ln < 10) out[row * 10 + ln] = acc[mt][0][r] + hb;
                            }
                    }
                }
                if (qp < 37) __syncthreads();         // Hs writes visible
            }
        }
    }
}

// ---------------------------------------------------------------------------
extern "C" void kernel_launch(void* const* d_in, const int* in_sizes, int n_in,
                              void* d_out, int out_size, void* d_ws, size_t ws_size,
                              hipStream_t stream) {
    (void)in_sizes; (void)n_in; (void)out_size; (void)ws_size;
    const float* x       = (const float*)d_in[0];
    const float* embed_w = (const float*)d_in[1];
    const float* embed_b = (const float*)d_in[2];
    const float* layer_w = (const float*)d_in[3];
    const float* head_w  = (const float*)d_in[4];
    const float* head_b  = (const float*)d_in[5];
    float* out = (float*)d_out;

    uint16_t* ws = (uint16_t*)d_ws;   // 190*5120 u16 = 1.95 MB

    resmlp_prep<<<926, 256, 0, stream>>>(embed_w, layer_w, head_w, ws);
    resmlp_main<<<512, 256, 0, stream>>>(x, embed_b, head_b, ws, out);
}

// Round 5
// 675.879 us; speedup vs baseline: 1.6691x; 1.6691x over previous
//
#include <hip/hip_runtime.h>
#include <cstdint>
#include <cstddef>

// ============================================================================
// ResMLP fused kernel for MI355X (gfx950) — round 5
//
//  - Prep (unchanged): weights -> uniform bf16 chunk-major stream ws[190][160][32]
//      c<25: embed (k pad 800), 25..184: 32 layers, 185..189: head (n pad 160).
//  - Main: grid 512 x 256 thr, __launch_bounds__(256,1) -> 512-reg budget,
//    NO spill (r4 failure: (256,2) capped at 256 regs -> 2.2GB scratch thrash).
//    128 rows/block, 4 waves = 2(mg:64 rows) x 2(ng:80 cols), tile 64x80.
//    B direct global->VGPR, 2-chunk ring; A ping-pong prefetch from LDS;
//    lgkm-only barriers (B loads stay in flight across panel boundaries);
//    x prefetched to registers during embed panels (disjoint from resid).
// ============================================================================

typedef __attribute__((ext_vector_type(8))) short bfrag8;   // 8 x bf16
typedef __attribute__((ext_vector_type(4))) float facc4;    // 4 x f32

#define MFMA16(a, b, c) __builtin_amdgcn_mfma_f32_16x16x32_bf16((a), (b), (c), 0, 0, 0)
// barrier that drains LDS ops only — vmem (B-ring/global loads) stays in flight
#define BARRIER_LGKM() asm volatile("s_waitcnt lgkmcnt(0)\n\ts_barrier" ::: "memory")

static __device__ __forceinline__ uint16_t f2bf16u(float v) {
    uint32_t u = __builtin_bit_cast(uint32_t, v);
    uint32_t r = u + 0x7FFFu + ((u >> 16) & 1u);
    return (uint16_t)(r >> 16);
}
static __device__ __forceinline__ uint32_t pack2_bf16(float lo, float hi) {
    return (uint32_t)f2bf16u(lo) | ((uint32_t)f2bf16u(hi) << 16);
}
static __device__ __forceinline__ uint32_t rtn_bits(float f) {   // round-half-up, hi16 = bf16
    return __builtin_bit_cast(uint32_t, f) + 0x8000u;
}

// ---------------------------------------------------------------------------
// Prep: transpose + cast weights into the uniform chunk-major stream.
// ---------------------------------------------------------------------------
__global__ __launch_bounds__(256) void resmlp_prep(
    const float* __restrict__ embed_w, const float* __restrict__ layer_w,
    const float* __restrict__ head_w, uint16_t* __restrict__ ws)
{
    int b = blockIdx.x;
    if (b == 925) {
        for (int idx = threadIdx.x; idx < 25600; idx += 256) {
            int n = idx / 160, k = idx - n * 160;
            float v = (n < 10) ? head_w[k * 10 + n] : 0.f;
            ws[(size_t)(185 + (k >> 5)) * 5120 + n * 32 + (k & 31)] = f2bf16u(v);
        }
        return;
    }
    __shared__ float tile[32][33];
    const float* src; int R, rt, ct; size_t chunkBase;
    if (b < 800) {
        int l = b / 25, t = b % 25; rt = t / 5; ct = t % 5;
        src = layer_w + (size_t)l * 25600; R = 160;
        chunkBase = (size_t)(25 + l * 5 + rt) * 5120;
    } else {
        int t = b - 800; rt = t / 5; ct = t % 5;
        src = embed_w; R = 784;
        chunkBase = (size_t)rt * 5120;
    }
    int tx = threadIdx.x & 31, ty = threadIdx.x >> 5;
#pragma unroll
    for (int j = 0; j < 4; ++j) {
        int r = rt * 32 + ty + j * 8, c = ct * 32 + tx;   // r=k, c=n
        tile[ty + j * 8][tx] = (r < R) ? src[(size_t)r * 160 + c] : 0.f;
    }
    __syncthreads();
#pragma unroll
    for (int j = 0; j < 4; ++j) {
        int n = ct * 32 + ty + j * 8;
        ws[chunkBase + n * 32 + tx] = f2bf16u(tile[tx][ty + j * 8]);
    }
}

// ---------------------------------------------------------------------------
// Direct stage of x group 0 (prologue only; exposed once).
// ---------------------------------------------------------------------------
__device__ __forceinline__ void stage_x_group0(const float* __restrict__ x,
                                               uint16_t* Hs, int r0, int tid)
{
    const int row = tid >> 1;
    const int h2  = tid & 1;
    const float* xr = x + (size_t)(r0 + row) * 784 + h2 * 80;
#pragma unroll
    for (int j = 0; j < 10; ++j) {          // 20 float4 per thread, pair-packed
        float4 a = *(const float4*)(xr + j * 8);
        float4 b = *(const float4*)(xr + j * 8 + 4);
        uint4 w;
        w.x = pack2_bf16(a.x, a.y); w.y = pack2_bf16(a.z, a.w);
        w.z = pack2_bf16(b.x, b.y); w.w = pack2_bf16(b.z, b.w);
        *(uint4*)((char*)Hs + row * 336 + h2 * 160 + j * 16) = w;
    }
}

// ---------------------------------------------------------------------------
__global__ __launch_bounds__(256, 1) void resmlp_main(
    const float* __restrict__ x,
    const float* __restrict__ embed_b,
    const float* __restrict__ head_b,
    const uint16_t* __restrict__ ws,
    float* __restrict__ out)
{
    __shared__ __align__(16) uint16_t Hs[128 * 168];   // 43008 B

    const int tid  = threadIdx.x;
    const int lane = tid & 63;
    const int wave = tid >> 6;
    const int mg = wave >> 1;          // 0..1  row group (64 rows)
    const int ng = wave & 1;           // 0..1  col group (80 cols)
    const int q  = lane >> 4;          // 0..3
    const int ln = lane & 15;          // 0..15
    const int NB = ng * 80;
    const int r0 = blockIdx.x * 128;
    const int srow = tid >> 1;         // x staging row
    const int h2x  = tid & 1;
    const bool oddl = (ln & 1) != 0;
    const uint32_t psel = oddl ? 0x03020706u : 0x07060302u;

    float bias[5];
#pragma unroll
    for (int nt = 0; nt < 5; ++nt) bias[nt] = embed_b[NB + nt * 16 + ln];
    const float hb = (ln < 10) ? head_b[ln] : 0.f;

    facc4 acc[4][5];
    facc4 resid[4][5];
    bfrag8 B0[5], B1[5];
    bfrag8 Ab[2][4];
    float4 xpf[20];                    // live only during embed panels (p<2)
#pragma unroll
    for (int mt = 0; mt < 4; ++mt)
#pragma unroll
        for (int nt = 0; nt < 5; ++nt) acc[mt][nt] = (facc4){0.f, 0.f, 0.f, 0.f};

    const uint16_t* wlane = ws + (NB + ln) * 32 + q * 8;

    // ---- prologue: stage x group 0; preload B chunks 0,1 ----
    stage_x_group0(x, Hs, r0, tid);
#pragma unroll
    for (int nt = 0; nt < 5; ++nt) {
        B0[nt] = *(const bfrag8*)(wlane + 0 * 5120 + nt * 512);
        B1[nt] = *(const bfrag8*)(wlane + 1 * 5120 + nt * 512);
    }
    BARRIER_LGKM();

    const int abase = (mg * 64 + ln) * 168 + q * 8;
    const uint16_t* wp = wlane + 2 * 5120;
    const int wb_base = (mg * 64 + q * 4 + (ln & 1)) * 336 + (NB + (ln & ~1)) * 2;

    for (int p = 0; p < 19; ++p) {
#pragma unroll
        for (int jj = 0; jj < 10; ++jj) {
            const int akk = jj % 5;                   // compile-time

            // fresh A at panel start (Hs just rewritten under barriers)
            if (jj == 0 || jj == 5) {
#pragma unroll
                for (int mt = 0; mt < 4; ++mt)
                    Ab[jj & 1][mt] = *(const bfrag8*)(Hs + abase + mt * (16 * 168) + akk * 32);
                // x prefetch for embed panels 1..4 (issue early, overlap MFMA)
                if (p < 2) {
                    const int g  = p * 2 + (jj == 5) + 1;    // 1..4
                    const int kc = g * 160 + h2x * 80;
                    const float* xr = x + (size_t)(r0 + srow) * 784 + kc;
#pragma unroll
                    for (int j = 0; j < 20; ++j) {
                        xpf[j] = (kc + j * 4 < 784) ? *(const float4*)(xr + j * 4)
                                                    : make_float4(0.f, 0.f, 0.f, 0.f);
                    }
                }
            }
            // A prefetch for next chunk (same panel only)
            if (jj != 4 && jj != 9) {
#pragma unroll
                for (int mt = 0; mt < 4; ++mt)
                    Ab[(jj + 1) & 1][mt] =
                        *(const bfrag8*)(Hs + abase + mt * (16 * 168) + (akk + 1) * 32);
            }

            bfrag8* Bc = (jj & 1) ? B1 : B0;
#pragma unroll
            for (int nt = 0; nt < 5; ++nt) {
                acc[0][nt] = MFMA16(Ab[jj & 1][0], Bc[nt], acc[0][nt]);
                acc[1][nt] = MFMA16(Ab[jj & 1][1], Bc[nt], acc[1][nt]);
                acc[2][nt] = MFMA16(Ab[jj & 1][2], Bc[nt], acc[2][nt]);
                acc[3][nt] = MFMA16(Ab[jj & 1][3], Bc[nt], acc[3][nt]);
                if (jj < 8 || p < 18)
                    Bc[nt] = *(const bfrag8*)(wp + nt * 512);   // reload for c+2
            }
            if (jj < 8 || p < 18) wp += 5120;

            // ---- panel boundary every 5 chunks ----
            if (jj == 4 || jj == 9) {
                const int qp = p * 2 + (jj == 9);     // 0..37
                BARRIER_LGKM();                       // everyone's A reads landed
                if (qp < 4) {
                    // commit prefetched x group qp+1 to Hs
#pragma unroll
                    for (int j = 0; j < 20; j += 2) {
                        uint4 w;
                        w.x = pack2_bf16(xpf[j].x,     xpf[j].y);
                        w.y = pack2_bf16(xpf[j].z,     xpf[j].w);
                        w.z = pack2_bf16(xpf[j + 1].x, xpf[j + 1].y);
                        w.w = pack2_bf16(xpf[j + 1].z, xpf[j + 1].w);
                        *(uint4*)((char*)Hs + srow * 336 + h2x * 160 + j * 8) = w;
                    }
                } else if (qp < 37) {
                    if (qp == 4) {
#pragma unroll
                        for (int mt = 0; mt < 4; ++mt)
#pragma unroll
                            for (int nt = 0; nt < 5; ++nt)
#pragma unroll
                                for (int r = 0; r < 4; ++r)
                                    resid[mt][nt][r] = acc[mt][nt][r] + bias[nt];
                    } else {
#pragma unroll
                        for (int mt = 0; mt < 4; ++mt)
#pragma unroll
                            for (int nt = 0; nt < 5; ++nt)
#pragma unroll
                                for (int r = 0; r < 4; ++r)
                                    resid[mt][nt][r] += fmaxf(acc[mt][nt][r], 0.f);
                    }
#pragma unroll
                    for (int mt = 0; mt < 4; ++mt) {
#pragma unroll
                        for (int nt = 0; nt < 5; ++nt) {
                            acc[mt][nt] = (facc4){0.f, 0.f, 0.f, 0.f};
#pragma unroll
                            for (int pr = 0; pr < 2; ++pr) {
                                const int rl = pr * 2;
                                float a  = oddl ? resid[mt][nt][rl + 1] : resid[mt][nt][rl];
                                float bx = oddl ? resid[mt][nt][rl]     : resid[mt][nt][rl + 1];
                                uint32_t br = rtn_bits(bx);
                                uint32_t pb = (uint32_t)__builtin_amdgcn_mov_dpp(
                                    (int)br, 0xB1, 0xF, 0xF, true);
                                uint32_t pk = __builtin_amdgcn_perm(pb, rtn_bits(a), psel);
                                *(uint32_t*)((char*)Hs + wb_base +
                                             mt * (16 * 336) + rl * 336 + nt * 32) = pk;
                            }
                        }
                    }
                } else {
                    // qp == 37: head epilogue + store
                    if (ng == 0) {
#pragma unroll
                        for (int mt = 0; mt < 4; ++mt)
#pragma unroll
                            for (int r = 0; r < 4; ++r) {
                                int row = r0 + mg * 64 + mt * 16 + q * 4 + r;
                                if (ln < 10) out[row * 10 + ln] = acc[mt][0][r] + hb;
                            }
                    }
                }
                if (qp < 37) BARRIER_LGKM();          // Hs writes visible
            }
        }
    }
}

// ---------------------------------------------------------------------------
extern "C" void kernel_launch(void* const* d_in, const int* in_sizes, int n_in,
                              void* d_out, int out_size, void* d_ws, size_t ws_size,
                              hipStream_t stream) {
    (void)in_sizes; (void)n_in; (void)out_size; (void)ws_size;
    const float* x       = (const float*)d_in[0];
    const float* embed_w = (const float*)d_in[1];
    const float* embed_b = (const float*)d_in[2];
    const float* layer_w = (const float*)d_in[3];
    const float* head_w  = (const float*)d_in[4];
    const float* head_b  = (const float*)d_in[5];
    float* out = (float*)d_out;

    uint16_t* ws = (uint16_t*)d_ws;   // 190*5120 u16 = 1.95 MB

    resmlp_prep<<<926, 256, 0, stream>>>(embed_w, layer_w, head_w, ws);
    resmlp_main<<<512, 256, 0, stream>>>(x, embed_b, head_b, ws, out);
}

// Round 6
// 502.118 us; speedup vs baseline: 2.2467x; 1.3461x over previous
//
#include <hip/hip_runtime.h>
#include <cstdint>
#include <cstddef>

// ============================================================================
// ResMLP fused kernel for MI355X (gfx950) — round 6
//
//  - zero kernel: clears ws (2.06 MB) every launch (ws is poisoned 0xAA).
//  - prep: builds 38 "LDS images" in ws, one per 160-K panel:
//      images 0..4  : embed W^T slices (K 0..799, zero-padded past 784)
//      images 5..36 : layer W^T (32 layers)
//      image  37    : head W^T (n 10..159 zeroed)
//    Image format = exactly what main wants in LDS: [160 n][168 k-elems]
//    bf16 (168-elem row stride -> 2-way-free LDS banking), padded to 54272 B.
//  - main: 512 blocks x 512 thr (8 waves = 4mg x 2ng, 128 rows/block,
//    1 block/CU, 2 rounds). Residual fp32 in regs; Hs (bf16 A-tile) in LDS.
//    W panel double-buffered in LDS, staged a FULL PANEL ahead with
//    global_load_lds (contiguous image copy, 53 x 1KB wave-calls) -> the
//    5-chunk inner loop has NO vmem at all; vmcnt(0) drains at the
//    panel-boundary barrier ~2000 cyc after issue (m97 stall avoided).
// ============================================================================

typedef __attribute__((ext_vector_type(8))) short bfrag8;   // 8 x bf16
typedef __attribute__((ext_vector_type(4))) float facc4;    // 4 x f32

#define MFMA16(a, b, c) __builtin_amdgcn_mfma_f32_16x16x32_bf16((a), (b), (c), 0, 0, 0)

#define NIMG       38
#define IMG_ELEMS  27136          // 160*168 + 256 pad (uint16)
#define IMG_BYTES  54272          // 53 x 1024
#define HS_ELEMS   21504          // 128*168

static __device__ __forceinline__ uint16_t f2bf16u(float v) {
    uint32_t u = __builtin_bit_cast(uint32_t, v);
    uint32_t r = u + 0x7FFFu + ((u >> 16) & 1u);
    return (uint16_t)(r >> 16);
}
static __device__ __forceinline__ uint32_t pack2_bf16(float lo, float hi) {
    return (uint32_t)f2bf16u(lo) | ((uint32_t)f2bf16u(hi) << 16);
}
static __device__ __forceinline__ uint32_t rtn_bits(float f) {
    return __builtin_bit_cast(uint32_t, f) + 0x8000u;
}
// async global->LDS, 16B per lane. lds dest = wave-uniform base + lane*16.
static __device__ __forceinline__ void gl_lds16(const void* g, void* l) {
    __builtin_amdgcn_global_load_lds(
        (const __attribute__((address_space(1))) uint32_t*)g,
        (__attribute__((address_space(3))) uint32_t*)l, 16, 0, 0);
}

// ---------------------------------------------------------------------------
// zero ws
// ---------------------------------------------------------------------------
__global__ __launch_bounds__(256) void resmlp_zero(uint4* __restrict__ ws4) {
    int i = blockIdx.x * 256 + threadIdx.x;
    if (i < (NIMG * IMG_ELEMS) / 8)
        ws4[i] = (uint4){0u, 0u, 0u, 0u};
}

// ---------------------------------------------------------------------------
// prep: transpose + cast weights into LDS-image format.
// Grid 950 = 38 images x 25 (5 k-tiles x 5 n-tiles), 256 thr.
// ---------------------------------------------------------------------------
__global__ __launch_bounds__(256) void resmlp_prep(
    const float* __restrict__ embed_w, const float* __restrict__ layer_w,
    const float* __restrict__ head_w, uint16_t* __restrict__ ws)
{
    int b = blockIdx.x;
    int img = b / 25, t = b % 25;
    int rt = t / 5, ct = t % 5;           // k-tile, n-tile
    int tx = threadIdx.x & 31, ty = threadIdx.x >> 5;

    __shared__ float tile[32][33];
#pragma unroll
    for (int j = 0; j < 4; ++j) {
        int k = rt * 32 + ty + j * 8;     // local k 0..159
        int n = ct * 32 + tx;             // n 0..159
        float v;
        if (img < 5) {
            int kg = img * 160 + k;
            v = (kg < 784) ? embed_w[(size_t)kg * 160 + n] : 0.f;
        } else if (img < 37) {
            v = layer_w[(size_t)(img - 5) * 25600 + (size_t)k * 160 + n];
        } else {
            v = (n < 10) ? head_w[k * 10 + n] : 0.f;
        }
        tile[ty + j * 8][tx] = v;
    }
    __syncthreads();
    uint16_t* dst = ws + (size_t)img * IMG_ELEMS;
#pragma unroll
    for (int j = 0; j < 4; ++j) {
        int n = ct * 32 + ty + j * 8;
        int k = rt * 32 + tx;
        dst[n * 168 + k] = f2bf16u(tile[tx][ty + j * 8]);
    }
}

// ---------------------------------------------------------------------------
// stage 128 rows x 160-col chunk of x (fp32 HBM) -> Hs bf16 (stride 168)
// ---------------------------------------------------------------------------
__device__ __forceinline__ void stage_x(const float* __restrict__ x,
                                        uint16_t* Hs, int r0, int tid, int g)
{
    const int row = tid >> 2;          // 0..127
    const int kc  = g * 160;
    const float* xr = x + (size_t)(r0 + row) * 784 + kc;
#pragma unroll
    for (int j = 0; j < 10; ++j) {
        int c4 = (tid & 3) + j * 4;    // float4 index 0..39
        float4 v = (kc + c4 * 4 < 784) ? *(const float4*)(xr + c4 * 4)
                                       : make_float4(0.f, 0.f, 0.f, 0.f);
        uint2 u;
        u.x = pack2_bf16(v.x, v.y);
        u.y = pack2_bf16(v.z, v.w);
        *(uint2*)((char*)Hs + row * 336 + c4 * 8) = u;
    }
}

// ---------------------------------------------------------------------------
__global__ __launch_bounds__(512, 2) void resmlp_main(
    const float* __restrict__ x,
    const float* __restrict__ embed_b,
    const float* __restrict__ head_b,
    const uint16_t* __restrict__ ws,
    float* __restrict__ out)
{
    extern __shared__ __align__(16) uint16_t lds[];
    uint16_t* Hs  = lds;                          // 21504 elems
    uint16_t* Wb0 = lds + HS_ELEMS;               // 27136 elems
    uint16_t* Wb1 = lds + HS_ELEMS + IMG_ELEMS;   // 27136 elems

    const int tid  = threadIdx.x;
    const int lane = tid & 63;
    const int wave = tid >> 6;         // 0..7
    const int mg = wave >> 1;          // 0..3  row group (32 rows)
    const int ng = wave & 1;           // 0..1  col group (80 cols)
    const int q  = lane >> 4;          // 0..3
    const int ln = lane & 15;          // 0..15
    const int NB = ng * 80;
    const int r0 = blockIdx.x * 128;
    const bool oddl = (ln & 1) != 0;
    const uint32_t psel = oddl ? 0x03020706u : 0x07060302u;

    float bias[5];
#pragma unroll
    for (int nt = 0; nt < 5; ++nt) bias[nt] = embed_b[NB + nt * 16 + ln];
    const float hb = (ln < 10) ? head_b[ln] : 0.f;

    facc4 acc[2][5];
    facc4 resid[2][5];
#pragma unroll
    for (int mt = 0; mt < 2; ++mt)
#pragma unroll
        for (int nt = 0; nt < 5; ++nt) acc[mt][nt] = (facc4){0.f, 0.f, 0.f, 0.f};

    const char* wsb = (const char*)ws;
    const int lb = lane * 16;          // lane byte offset within a 1KB call

    // ---- prologue: stage x group 0 + W image 0 into Wb0 ----
    stage_x(x, Hs, r0, tid, 0);
#pragma unroll
    for (int i = 0; i < 7; ++i) {
        int idx = wave * 7 + i;
        if (idx < 53)
            gl_lds16(wsb + idx * 1024 + lb, (char*)Wb0 + idx * 1024 + lb);
    }
    __syncthreads();                   // drains vmcnt(0) too

    const int abase = (mg * 32 + ln) * 168 + q * 8;   // A elem offset in Hs
    const int bbase = (NB + ln) * 168 + q * 8;        // B elem offset in W buf
    const int wb_base = (mg * 32 + q * 4 + (ln & 1)) * 336 + (NB + (ln & ~1)) * 2;

    for (int p = 0; p < 38; ++p) {
        const uint16_t* Wcur = (p & 1) ? Wb1 : Wb0;

        // ---- stage panel p+1 into the other buffer (async, panel-deep) ----
        if (p < 37) {
            char* Wnx = (char*)((p & 1) ? Wb0 : Wb1);
            const char* src = wsb + (size_t)(p + 1) * IMG_BYTES;
#pragma unroll
            for (int i = 0; i < 7; ++i) {
                int idx = wave * 7 + i;
                if (idx < 53)
                    gl_lds16(src + idx * 1024 + lb, Wnx + idx * 1024 + lb);
            }
        }

        // ---- compute 5 chunks from Wcur (no vmem in here) ----
#pragma unroll
        for (int k = 0; k < 5; ++k) {
            bfrag8 a0 = *(const bfrag8*)(Hs + abase + 0 * (16 * 168) + k * 32);
            bfrag8 a1 = *(const bfrag8*)(Hs + abase + 1 * (16 * 168) + k * 32);
#pragma unroll
            for (int nt = 0; nt < 5; ++nt) {
                bfrag8 bf = *(const bfrag8*)(Wcur + bbase + nt * (16 * 168) + k * 32);
                acc[0][nt] = MFMA16(a0, bf, acc[0][nt]);
                acc[1][nt] = MFMA16(a1, bf, acc[1][nt]);
            }
        }

        // ---- panel boundary ----
        __syncthreads();               // A/B reads done; staged p+1 landed
        if (p < 4) {
            stage_x(x, Hs, r0, tid, p + 1);
        } else if (p < 37) {
            if (p == 4) {
#pragma unroll
                for (int mt = 0; mt < 2; ++mt)
#pragma unroll
                    for (int nt = 0; nt < 5; ++nt)
#pragma unroll
                        for (int r = 0; r < 4; ++r)
                            resid[mt][nt][r] = acc[mt][nt][r] + bias[nt];
            } else {
#pragma unroll
                for (int mt = 0; mt < 2; ++mt)
#pragma unroll
                    for (int nt = 0; nt < 5; ++nt)
#pragma unroll
                        for (int r = 0; r < 4; ++r)
                            resid[mt][nt][r] += fmaxf(acc[mt][nt][r], 0.f);
            }
#pragma unroll
            for (int mt = 0; mt < 2; ++mt) {
#pragma unroll
                for (int nt = 0; nt < 5; ++nt) {
                    acc[mt][nt] = (facc4){0.f, 0.f, 0.f, 0.f};
#pragma unroll
                    for (int pr = 0; pr < 2; ++pr) {
                        const int rl = pr * 2;
                        float a  = oddl ? resid[mt][nt][rl + 1] : resid[mt][nt][rl];
                        float bx = oddl ? resid[mt][nt][rl]     : resid[mt][nt][rl + 1];
                        uint32_t br = rtn_bits(bx);
                        uint32_t pb = (uint32_t)__builtin_amdgcn_mov_dpp(
                            (int)br, 0xB1, 0xF, 0xF, true);        // pair swap
                        uint32_t pk = __builtin_amdgcn_perm(pb, rtn_bits(a), psel);
                        *(uint32_t*)((char*)Hs + wb_base +
                                     mt * (16 * 336) + rl * 336 + nt * 32) = pk;
                    }
                }
            }
        } else {
            // p == 37: head epilogue + store
            if (ng == 0) {
#pragma unroll
                for (int mt = 0; mt < 2; ++mt)
#pragma unroll
                    for (int r = 0; r < 4; ++r) {
                        int row = r0 + mg * 32 + mt * 16 + q * 4 + r;
                        if (ln < 10) out[row * 10 + ln] = acc[mt][0][r] + hb;
                    }
            }
        }
        if (p < 37) __syncthreads();   // Hs writes visible before next panel
    }
}

// ---------------------------------------------------------------------------
extern "C" void kernel_launch(void* const* d_in, const int* in_sizes, int n_in,
                              void* d_out, int out_size, void* d_ws, size_t ws_size,
                              hipStream_t stream) {
    (void)in_sizes; (void)n_in; (void)out_size; (void)ws_size;
    const float* x       = (const float*)d_in[0];
    const float* embed_w = (const float*)d_in[1];
    const float* embed_b = (const float*)d_in[2];
    const float* layer_w = (const float*)d_in[3];
    const float* head_w  = (const float*)d_in[4];
    const float* head_b  = (const float*)d_in[5];
    float* out = (float*)d_out;

    uint16_t* ws = (uint16_t*)d_ws;   // 38 * 27136 u16 = 2.06 MB

    const int dynLds = (HS_ELEMS + 2 * IMG_ELEMS) * 2;   // 151552 B
    static bool attr_set = false;     // host-side config, not stream work
    (void)hipFuncSetAttribute((const void*)resmlp_main,
                              hipFuncAttributeMaxDynamicSharedMemorySize, dynLds);

    resmlp_zero<<<504, 256, 0, stream>>>((uint4*)d_ws);
    resmlp_prep<<<950, 256, 0, stream>>>(embed_w, layer_w, head_w, ws);
    resmlp_main<<<512, 512, dynLds, stream>>>(x, embed_b, head_b, ws, out);
}